// Round 3
// baseline (3775.340 us; speedup 1.0000x reference)
//
#include <hip/hip_runtime.h>
#include <stdint.h>

#define H_ 64
#define W_ 64
#define D_ 256
#define U_ 512
#define KTOT 1280           // 256 (x) + 512 (h_up) + 512 (h_left)
#define CELL_ELT (32 * U_)  // elements per cell in hgrid

typedef __attribute__((ext_vector_type(8))) _Float16 half8;
typedef __attribute__((ext_vector_type(8))) unsigned short ushort8;
typedef __attribute__((ext_vector_type(4))) float f32x4;

__device__ __forceinline__ unsigned short f2h(float f) {
    _Float16 h = (_Float16)f;  // RNE
    return __builtin_bit_cast(unsigned short, h);
}

// WcT[n][k] fp16: stacked [wax; w0; w1] transposed. n in [0,512), k in [0,1280).
__global__ void prep_kernel(const float* __restrict__ wax,
                            const float* __restrict__ w0,
                            const float* __restrict__ w1,
                            unsigned short* __restrict__ wcT) {
    int n = blockIdx.x;
    for (int k = threadIdx.x; k < KTOT; k += blockDim.x) {
        float v;
        if (k < D_)            v = wax[(size_t)k * U_ + n];
        else if (k < D_ + U_)  v = w0[(size_t)(k - D_) * U_ + n];
        else                   v = w1[(size_t)(k - D_ - U_) * U_ + n];
        wcT[(size_t)n * KTOT + k] = f2h(v);
    }
}

// Persistent kernel: block = (column j, n-chunk nc). 256 blocks, 1 per CU.
__global__ __launch_bounds__(256, 1) void mdrnn_persistent(
    const float* __restrict__ x,
    const unsigned short* __restrict__ wcT,
    unsigned short* __restrict__ hgrid,
    int* flags,
    const float* __restrict__ ba,
    float* __restrict__ out)
{
    __shared__ char smb[32 * 2560];  // 80 KB: 32 rows x 1280 fp16 (x|up|left), swizzled

    const int j  = (int)blockIdx.x >> 2;
    const int nc = (int)blockIdx.x & 3;
    const int t    = threadIdx.x;
    const int lane = t & 63;
    const int wv   = t >> 6;     // 4 waves -> 32 N-cols each
    const int l15  = lane & 15;
    const int lh   = lane >> 4;  // k-group 0..3
    const int r    = t >> 3;     // staging row 0..31
    const int c8   = t & 7;
    const int swzr = (r & 7) << 4;
    const int swzl = (l15 & 7) << 4;

    // ---- weight slice (128 N-cols x 1280 K) into registers: 320 VGPR ----
    half8 breg[2][40];
    {
        const unsigned short* wb = wcT + (size_t)(nc * 128 + wv * 32 + l15) * KTOT + lh * 8;
        #pragma unroll
        for (int nt = 0; nt < 2; ++nt)
            #pragma unroll
            for (int ks = 0; ks < 40; ++ks)
                breg[nt][ks] = *reinterpret_cast<const half8*>(wb + (size_t)nt * 16 * KTOT + ks * 32);
    }
    const float bav0 = ba[nc * 128 + wv * 32 + l15];
    const float bav1 = ba[nc * 128 + wv * 32 + 16 + l15];

    const float* xbase = x + (size_t)r * H_ * W_ * D_ + c8 * 32;
    char* xrow = smb + r * 2560;

    #pragma clang loop unroll(disable)
    for (int i = 0; i < H_; ++i) {
        const int cell = i * W_ + j;

        // issue x loads early: latency hides under the flag spin
        float4 xa[8];
        {
            const float4* xs = reinterpret_cast<const float4*>(xbase + (size_t)(i * W_ + j) * D_);
            #pragma unroll
            for (int q = 0; q < 8; ++q) xa[q] = xs[q];
        }

        // wait for up (own group, row i-1) and left (group j-1, row i)
        if (i > 0 || j > 0) {
            int* fu = (i > 0) ? &flags[cell - W_] : nullptr;
            int* fl = (j > 0) ? &flags[cell - 1] : nullptr;
            for (;;) {
                int a = fu ? __hip_atomic_load(fu, __ATOMIC_ACQUIRE, __HIP_MEMORY_SCOPE_AGENT) : 4;
                int b = fl ? __hip_atomic_load(fl, __ATOMIC_ACQUIRE, __HIP_MEMORY_SCOPE_AGENT) : 4;
                if (a >= 4 && b >= 4) break;
                __builtin_amdgcn_s_sleep(1);
            }
        }

        // x -> LDS (fp16, swizzled). k region [0,256)
        #pragma unroll
        for (int s = 0; s < 4; ++s) {
            float4 a = xa[2 * s], b = xa[2 * s + 1];
            ushort8 o;
            o[0] = f2h(a.x); o[1] = f2h(a.y); o[2] = f2h(a.z); o[3] = f2h(a.w);
            o[4] = f2h(b.x); o[5] = f2h(b.y); o[6] = f2h(b.z); o[7] = f2h(b.w);
            *reinterpret_cast<ushort8*>(xrow + ((c8 * 64 + s * 16) ^ swzr)) = o;
        }

        // frontier rows -> LDS. up: region [512,1536) bytes; left: [1536,2560)
        if (i > 0) {
            const ushort8* us = reinterpret_cast<const ushort8*>(
                hgrid + (size_t)(cell - W_) * CELL_ELT + (size_t)r * U_ + c8 * 64);
            ushort8 ub[8];
            #pragma unroll
            for (int s = 0; s < 8; ++s) ub[s] = us[s];
            #pragma unroll
            for (int s = 0; s < 8; ++s)
                *reinterpret_cast<ushort8*>(xrow + ((512 + c8 * 128 + s * 16) ^ swzr)) = ub[s];
        }
        if (j > 0) {
            const ushort8* ls = reinterpret_cast<const ushort8*>(
                hgrid + (size_t)(cell - 1) * CELL_ELT + (size_t)r * U_ + c8 * 64);
            ushort8 lb[8];
            #pragma unroll
            for (int s = 0; s < 8; ++s) lb[s] = ls[s];
            #pragma unroll
            for (int s = 0; s < 8; ++s)
                *reinterpret_cast<ushort8*>(xrow + ((1536 + c8 * 128 + s * 16) ^ swzr)) = lb[s];
        }
        __syncthreads();

        // ---- MFMA: C(32 x 128chunk) += A(32 x 1280) * B ----
        f32x4 z = {0.f, 0.f, 0.f, 0.f};
        f32x4 acc00 = z, acc01 = z, acc10 = z, acc11 = z;
        const char* arow0 = smb + l15 * 2560;
        const char* arow1 = smb + (16 + l15) * 2560;

#define MSTEP(ks)                                                                              \
        {                                                                                      \
            half8 af0 = *reinterpret_cast<const half8*>(arow0 + (((ks) * 64 + lh * 16) ^ swzl)); \
            half8 af1 = *reinterpret_cast<const half8*>(arow1 + (((ks) * 64 + lh * 16) ^ swzl)); \
            acc00 = __builtin_amdgcn_mfma_f32_16x16x32_f16(af0, breg[0][(ks)], acc00, 0, 0, 0); \
            acc01 = __builtin_amdgcn_mfma_f32_16x16x32_f16(af0, breg[1][(ks)], acc01, 0, 0, 0); \
            acc10 = __builtin_amdgcn_mfma_f32_16x16x32_f16(af1, breg[0][(ks)], acc10, 0, 0, 0); \
            acc11 = __builtin_amdgcn_mfma_f32_16x16x32_f16(af1, breg[1][(ks)], acc11, 0, 0, 0); \
        }

        #pragma unroll
        for (int ks = 0; ks < 8; ++ks) MSTEP(ks)
        if (i > 0) {
            #pragma unroll
            for (int ks = 8; ks < 24; ++ks) MSTEP(ks)
        }
        if (j > 0) {
            #pragma unroll
            for (int ks = 24; ks < 40; ++ks) MSTEP(ks)
        }
#undef MSTEP

        // ---- epilogue: bias, tanh, write frontier ----
        unsigned short* hw = hgrid + (size_t)cell * CELL_ELT;
        const bool lastcell = (i == H_ - 1) && (j == W_ - 1);
        const int nc0 = nc * 128 + wv * 32 + l15;
        #pragma unroll
        for (int mt = 0; mt < 2; ++mt) {
            f32x4 a0 = mt ? acc10 : acc00;
            f32x4 a1 = mt ? acc11 : acc01;
            #pragma unroll
            for (int rr = 0; rr < 4; ++rr) {
                int brow = mt * 16 + lh * 4 + rr;  // C/D: row=(lane>>4)*4+reg
                float v0 = fminf(fmaxf(a0[rr] + bav0, -15.f), 15.f);
                float v1 = fminf(fmaxf(a1[rr] + bav1, -15.f), 15.f);
                float e0 = __expf(2.f * v0), e1 = __expf(2.f * v1);
                float th0 = (e0 - 1.f) / (e0 + 1.f);
                float th1 = (e1 - 1.f) / (e1 + 1.f);
                hw[(size_t)brow * U_ + nc0]      = f2h(th0);
                hw[(size_t)brow * U_ + nc0 + 16] = f2h(th1);
                if (lastcell) {
                    out[(size_t)brow * U_ + nc0]      = th0;
                    out[(size_t)brow * U_ + nc0 + 16] = th1;
                }
            }
        }

        __syncthreads();  // drains vmcnt(0): all block stores complete before release
        if (t == 0)
            __hip_atomic_fetch_add(&flags[cell], 1, __ATOMIC_RELEASE, __HIP_MEMORY_SCOPE_AGENT);
    }
}

extern "C" void kernel_launch(void* const* d_in, const int* in_sizes, int n_in,
                              void* d_out, int out_size, void* d_ws, size_t ws_size,
                              hipStream_t stream) {
    const float* x   = (const float*)d_in[0];
    const float* wax = (const float*)d_in[1];
    const float* w0  = (const float*)d_in[2];
    const float* w1  = (const float*)d_in[3];
    const float* ba  = (const float*)d_in[4];
    float* out = (float*)d_out;

    // ws layout: WcT 1.25MB | flags 16KB | hgrid 128MB  (ws >= 512MB observed)
    constexpr size_t WCT_BYTES = (size_t)U_ * KTOT * 2;               // 1,310,720 (4K-aligned)
    constexpr size_t FLAGS_OFF = WCT_BYTES;
    constexpr size_t FLAGS_BYTES = (size_t)H_ * W_ * sizeof(int);     // 16,384
    constexpr size_t HGRID_OFF = FLAGS_OFF + FLAGS_BYTES;             // 4K-aligned

    unsigned short* wcT   = (unsigned short*)d_ws;
    int*            flags = (int*)((char*)d_ws + FLAGS_OFF);
    unsigned short* hgrid = (unsigned short*)((char*)d_ws + HGRID_OFF);

    hipMemsetAsync(flags, 0, FLAGS_BYTES, stream);
    prep_kernel<<<dim3(U_), dim3(256), 0, stream>>>(wax, w0, w1, wcT);
    mdrnn_persistent<<<dim3(W_ * 4), dim3(256), 0, stream>>>(x, wcT, hgrid, flags, ba, out);
}

// Round 5
// 2418.155 us; speedup vs baseline: 1.5612x; 1.5612x over previous
//
#include <hip/hip_runtime.h>
#include <stdint.h>

#define H_ 64
#define W_ 64
#define D_ 256
#define U_ 512
#define KREC 1024           // 512 (h_up, w0) + 512 (h_left, w1)
#define CELL_ELT (32 * U_)  // elements per cell in hgrid

typedef __attribute__((ext_vector_type(8))) _Float16 half8;
typedef __attribute__((ext_vector_type(8))) unsigned short ushort8;
typedef __attribute__((ext_vector_type(4))) float f32x4;

__device__ __forceinline__ unsigned short f2h(float f) {
    _Float16 h = (_Float16)f;  // RNE
    return __builtin_bit_cast(unsigned short, h);
}

// wcT2[n][k] fp16: [w0; w1] transposed. n in [0,512), k in [0,1024).
__global__ void prep_w(const float* __restrict__ w0,
                       const float* __restrict__ w1,
                       unsigned short* __restrict__ wcT2) {
    int n = blockIdx.x;
    for (int k = threadIdx.x; k < KREC; k += blockDim.x) {
        float v = (k < U_) ? w0[(size_t)k * U_ + n] : w1[(size_t)(k - U_) * U_ + n];
        wcT2[(size_t)n * KREC + k] = f2h(v);
    }
}

// waxT[n][k] fp16, n in [0,512), k in [0,256)
__global__ void prep_waxT(const float* __restrict__ wax,
                          unsigned short* __restrict__ waxT) {
    int n = blockIdx.x;
    for (int k = threadIdx.x; k < D_; k += blockDim.x)
        waxT[(size_t)n * D_ + k] = f2h(wax[(size_t)k * U_ + n]);
}

// Z = x@wax + ba per cell, stored FRAGMENT-ORDERED fp32:
// zfb[cell][gw 16][lane 64][16] where value idx = mt*8 + ntp*4 + rr maps to
// (row = mt*16 + (lane>>4)*4 + rr, col = gw*32 + ntp*16 + (lane&15)).
__global__ __launch_bounds__(256) void prep_z(
    const float* __restrict__ x,
    const unsigned short* __restrict__ waxT,
    const float* __restrict__ ba,
    float* __restrict__ zfb)
{
    __shared__ char xs[32 * 512];  // 16KB fp16, swizzled rows (512B stride)
    const int cell = blockIdx.x;
    const int t = threadIdx.x, lane = t & 63, wv = t >> 6;
    const int l15 = lane & 15, lh = lane >> 4;
    const int r = t >> 3, c8 = t & 7;
    const int swzr = (r & 7) << 4;
    const int swzl = (l15 & 7) << 4;

    // stage x[batch r][cell][c8*32 .. +32] -> fp16 LDS
    {
        const float4* src = reinterpret_cast<const float4*>(
            x + (size_t)r * (H_ * W_ * D_) + (size_t)cell * D_ + c8 * 32);
        float4 f[8];
        #pragma unroll
        for (int q = 0; q < 8; ++q) f[q] = src[q];
        #pragma unroll
        for (int s = 0; s < 4; ++s) {
            float4 a = f[2 * s], b = f[2 * s + 1];
            ushort8 o;
            o[0] = f2h(a.x); o[1] = f2h(a.y); o[2] = f2h(a.z); o[3] = f2h(a.w);
            o[4] = f2h(b.x); o[5] = f2h(b.y); o[6] = f2h(b.z); o[7] = f2h(b.w);
            *reinterpret_cast<ushort8*>(xs + ((r * 512 + c8 * 64 + s * 16) ^ swzr)) = o;
        }
    }
    __syncthreads();

    // wave wv computes cols [wv*128, wv*128+128): 8 n-tiles, K=256
    f32x4 zero = {0.f, 0.f, 0.f, 0.f};
    f32x4 acc[2][8];
    #pragma unroll
    for (int m = 0; m < 2; ++m)
        #pragma unroll
        for (int n = 0; n < 8; ++n) acc[m][n] = zero;

    const char* ar0 = xs + l15 * 512;
    const char* ar1 = xs + (16 + l15) * 512;
    #pragma unroll
    for (int ks = 0; ks < 8; ++ks) {
        half8 af0 = *reinterpret_cast<const half8*>(ar0 + ((ks * 64 + lh * 16) ^ swzl));
        half8 af1 = *reinterpret_cast<const half8*>(ar1 + ((ks * 64 + lh * 16) ^ swzl));
        #pragma unroll
        for (int ntg = 0; ntg < 8; ++ntg) {
            int col = wv * 128 + ntg * 16 + l15;
            half8 bf = *reinterpret_cast<const half8*>(waxT + (size_t)col * D_ + ks * 32 + lh * 8);
            acc[0][ntg] = __builtin_amdgcn_mfma_f32_16x16x32_f16(af0, bf, acc[0][ntg], 0, 0, 0);
            acc[1][ntg] = __builtin_amdgcn_mfma_f32_16x16x32_f16(af1, bf, acc[1][ntg], 0, 0, 0);
        }
    }

    // write fragment-ordered Z (+ba), 16 contiguous fp32 per lane per slot
    #pragma unroll
    for (int s = 0; s < 4; ++s) {
        float* dst = zfb + (((size_t)cell * 16 + wv * 4 + s) * 64 + lane) * 16;
        #pragma unroll
        for (int mt = 0; mt < 2; ++mt)
            #pragma unroll
            for (int ntp = 0; ntp < 2; ++ntp) {
                float bav = ba[wv * 128 + s * 32 + ntp * 16 + l15];
                f32x4 o;
                o[0] = acc[mt][s * 2 + ntp][0] + bav;
                o[1] = acc[mt][s * 2 + ntp][1] + bav;
                o[2] = acc[mt][s * 2 + ntp][2] + bav;
                o[3] = acc[mt][s * 2 + ntp][3] + bav;
                *reinterpret_cast<f32x4*>(dst + mt * 8 + ntp * 4) = o;
            }
    }
}

// Persistent recurrence: block = (column j, n-chunk nc). 256 blocks, 1/CU.
__global__ __launch_bounds__(256, 1) void mdrnn_persistent(
    const unsigned short* __restrict__ wcT2,
    const float* __restrict__ zfb,
    unsigned short* __restrict__ hgrid,
    int* flags,
    float* __restrict__ out)
{
    __shared__ char smb[32 * 2048];  // 64KB: 32 rows x (up 1024B | left 1024B), swizzled

    const int j  = (int)blockIdx.x >> 2;
    const int nc = (int)blockIdx.x & 3;
    const int t = threadIdx.x, lane = t & 63, wv = t >> 6;
    const int l15 = lane & 15, lh = lane >> 4;
    const int r = t >> 3, c8 = t & 7;
    const int swzr = (r & 7) << 4;
    const int swzl = (l15 & 7) << 4;
    const int gw = nc * 4 + wv;

    // recurrent weights (128 N-cols x 1024 K) in registers: 256 VGPR
    half8 breg[2][32];
    {
        const unsigned short* wb = wcT2 + (size_t)(nc * 128 + wv * 32 + l15) * KREC + lh * 8;
        #pragma unroll
        for (int nt = 0; nt < 2; ++nt)
            #pragma unroll
            for (int ks = 0; ks < 32; ++ks)
                breg[nt][ks] = *reinterpret_cast<const half8*>(wb + (size_t)nt * 16 * KREC + ks * 32);
    }

    #pragma clang loop unroll(disable)
    for (int i = 0; i < H_; ++i) {
        const int cell = i * W_ + j;

        // Z prefetch: issued before the poll, lands during the wait
        const f32x4* zp = reinterpret_cast<const f32x4*>(
            zfb + (((size_t)cell * 16 + gw) * 64 + lane) * 16);
        f32x4 z0 = zp[0], z1 = zp[1], z2 = zp[2], z3 = zp[3];

        // wave 0 polls; other waves park at the barrier (wg-acquire fence orders their loads)
        if (wv == 0 && (i > 0 || j > 0)) {
            int* fu = flags + (cell - W_);
            int* fl = flags + (cell - 1);
            const bool nu = (i > 0), nl = (j > 0);
            for (;;) {
                int a = nu ? __hip_atomic_load(fu, __ATOMIC_ACQUIRE, __HIP_MEMORY_SCOPE_AGENT) : 4;
                int b = nl ? __hip_atomic_load(fl, __ATOMIC_ACQUIRE, __HIP_MEMORY_SCOPE_AGENT) : 4;
                if (a >= 4 && b >= 4) break;
                __builtin_amdgcn_s_sleep(4);
            }
        }
        __syncthreads();

        // single-shot staging: both frontiers -> LDS (64KB, one memory phase)
        if (i > 0) {
            const ushort8* us = reinterpret_cast<const ushort8*>(
                hgrid + (size_t)(cell - W_) * CELL_ELT + (size_t)r * U_ + c8 * 64);
            ushort8 ub[8];
            #pragma unroll
            for (int s = 0; s < 8; ++s) ub[s] = us[s];
            #pragma unroll
            for (int s = 0; s < 8; ++s)
                *reinterpret_cast<ushort8*>(smb + ((r * 2048 + c8 * 128 + s * 16) ^ swzr)) = ub[s];
        }
        if (j > 0) {
            const ushort8* ls = reinterpret_cast<const ushort8*>(
                hgrid + (size_t)(cell - 1) * CELL_ELT + (size_t)r * U_ + c8 * 64);
            ushort8 lb[8];
            #pragma unroll
            for (int s = 0; s < 8; ++s) lb[s] = ls[s];
            #pragma unroll
            for (int s = 0; s < 8; ++s)
                *reinterpret_cast<ushort8*>(smb + ((r * 2048 + 1024 + c8 * 128 + s * 16) ^ swzr)) = lb[s];
        }
        __syncthreads();

        f32x4 zero = {0.f, 0.f, 0.f, 0.f};
        f32x4 acc00 = zero, acc01 = zero, acc10 = zero, acc11 = zero;
        const char* ar0 = smb + l15 * 2048;
        const char* ar1 = smb + (16 + l15) * 2048;

#define MSTEP(ks)                                                                                \
        {                                                                                        \
            half8 af0 = *reinterpret_cast<const half8*>(ar0 + (((ks) * 64 + lh * 16) ^ swzl));   \
            half8 af1 = *reinterpret_cast<const half8*>(ar1 + (((ks) * 64 + lh * 16) ^ swzl));   \
            acc00 = __builtin_amdgcn_mfma_f32_16x16x32_f16(af0, breg[0][(ks)], acc00, 0, 0, 0);  \
            acc01 = __builtin_amdgcn_mfma_f32_16x16x32_f16(af0, breg[1][(ks)], acc01, 0, 0, 0);  \
            acc10 = __builtin_amdgcn_mfma_f32_16x16x32_f16(af1, breg[0][(ks)], acc10, 0, 0, 0);  \
            acc11 = __builtin_amdgcn_mfma_f32_16x16x32_f16(af1, breg[1][(ks)], acc11, 0, 0, 0);  \
        }
        if (i > 0) {
            #pragma unroll
            for (int ks = 0; ks < 16; ++ks) MSTEP(ks)
        }
        if (j > 0) {
            #pragma unroll
            for (int ks = 16; ks < 32; ++ks) MSTEP(ks)
        }
#undef MSTEP

        // epilogue: acc + Z, tanh, write frontier (fp16) + out (fp32)
        unsigned short* hw = hgrid + (size_t)cell * CELL_ELT;
        const bool lastcell = (i == H_ - 1) && (j == W_ - 1);
        const int col0 = nc * 128 + wv * 32 + l15;
        #pragma unroll
        for (int mt = 0; mt < 2; ++mt) {
            f32x4 a0 = mt ? acc10 : acc00;
            f32x4 a1 = mt ? acc11 : acc01;
            f32x4 zq0 = mt ? z2 : z0;
            f32x4 zq1 = mt ? z3 : z1;
            #pragma unroll
            for (int rr = 0; rr < 4; ++rr) {
                int row = mt * 16 + lh * 4 + rr;  // C/D: row=(lane>>4)*4+reg
                float v0 = fminf(fmaxf(a0[rr] + zq0[rr], -15.f), 15.f);
                float v1 = fminf(fmaxf(a1[rr] + zq1[rr], -15.f), 15.f);
                float e0 = __expf(2.f * v0), e1 = __expf(2.f * v1);
                float th0 = (e0 - 1.f) / (e0 + 1.f);
                float th1 = (e1 - 1.f) / (e1 + 1.f);
                hw[(size_t)row * U_ + col0]      = f2h(th0);
                hw[(size_t)row * U_ + col0 + 16] = f2h(th1);
                if (lastcell) {
                    out[(size_t)row * U_ + col0]      = th0;
                    out[(size_t)row * U_ + col0 + 16] = th1;
                }
            }
        }

        __syncthreads();  // drains all waves' stores (vmcnt 0) before release
        if (t == 0)
            __hip_atomic_fetch_add(&flags[cell], 1, __ATOMIC_RELEASE, __HIP_MEMORY_SCOPE_AGENT);
    }
}

extern "C" void kernel_launch(void* const* d_in, const int* in_sizes, int n_in,
                              void* d_out, int out_size, void* d_ws, size_t ws_size,
                              hipStream_t stream) {
    const float* x   = (const float*)d_in[0];
    const float* wax = (const float*)d_in[1];
    const float* w0  = (const float*)d_in[2];
    const float* w1  = (const float*)d_in[3];
    const float* ba  = (const float*)d_in[4];
    float* out = (float*)d_out;

    // ws layout (total ~386 MiB; observed ws >= 512 MiB):
    // wcT2 1MiB | waxT 256KiB | flags 16KiB | (pad to 2MiB) zfb 256MiB | hgrid 128MiB
    char* w = (char*)d_ws;
    unsigned short* wcT2  = (unsigned short*)(w);
    unsigned short* waxT  = (unsigned short*)(w + (1u << 20));
    int*            flags = (int*)(w + (1u << 20) + (256u << 10));
    float*          zfb   = (float*)(w + (2u << 20));
    unsigned short* hgrid = (unsigned short*)(w + (2u << 20) + ((size_t)256 << 20));

    (void)hipMemsetAsync(flags, 0, (size_t)H_ * W_ * sizeof(int), stream);
    prep_w   <<<dim3(U_), dim3(256), 0, stream>>>(w0, w1, wcT2);
    prep_waxT<<<dim3(U_), dim3(256), 0, stream>>>(wax, waxT);
    prep_z   <<<dim3(H_ * W_), dim3(256), 0, stream>>>(x, waxT, ba, zfb);
    mdrnn_persistent<<<dim3(W_ * 4), dim3(256), 0, stream>>>(wcT2, zfb, hgrid, flags, out);
}

// Round 6
// 1948.082 us; speedup vs baseline: 1.9380x; 1.2413x over previous
//
#include <hip/hip_runtime.h>
#include <stdint.h>

#define H_ 64
#define W_ 64
#define D_ 256
#define U_ 512
#define KREC 1024           // 512 (h_up, w0) + 512 (h_left, w1)
#define CELL_ELT (32 * U_)  // elements per cell in hgrid

typedef __attribute__((ext_vector_type(8))) _Float16 half8;
typedef __attribute__((ext_vector_type(8))) unsigned short ushort8;
typedef __attribute__((ext_vector_type(4))) float f32x4;

__device__ __forceinline__ unsigned short f2h(float f) {
    _Float16 h = (_Float16)f;  // RNE
    return __builtin_bit_cast(unsigned short, h);
}

// Bank-conflict-free LDS offset: fold byte-addr bits [9:7] and row into bits [6:4].
// Same function applied on write and read (both-sides-or-neither).
__device__ __forceinline__ int swzo(int r, int o) {
    return o ^ (((r ^ (o >> 7)) & 7) << 4);
}

// wcT2[n][k] fp16: [w0; w1] transposed. n in [0,512), k in [0,1024).
__global__ void prep_w(const float* __restrict__ w0,
                       const float* __restrict__ w1,
                       unsigned short* __restrict__ wcT2) {
    int n = blockIdx.x;
    for (int k = threadIdx.x; k < KREC; k += blockDim.x) {
        float v = (k < U_) ? w0[(size_t)k * U_ + n] : w1[(size_t)(k - U_) * U_ + n];
        wcT2[(size_t)n * KREC + k] = f2h(v);
    }
}

// waxT[n][k] fp16, n in [0,512), k in [0,256)
__global__ void prep_waxT(const float* __restrict__ wax,
                          unsigned short* __restrict__ waxT) {
    int n = blockIdx.x;
    for (int k = threadIdx.x; k < D_; k += blockDim.x)
        waxT[(size_t)n * D_ + k] = f2h(wax[(size_t)k * U_ + n]);
}

// Z = x@wax + ba per cell, stored FRAGMENT-ORDERED fp32:
// zfb[cell][gw 16][lane 64][16]; value idx = mt*8 + ntp*4 + rr maps to
// (row = mt*16 + (lane>>4)*4 + rr, col = gw*32 + ntp*16 + (lane&15)).
__global__ __launch_bounds__(256) void prep_z(
    const float* __restrict__ x,
    const unsigned short* __restrict__ waxT,
    const float* __restrict__ ba,
    float* __restrict__ zfb)
{
    __shared__ char xs[32 * 512];  // 16KB fp16, swizzled
    const int cell = blockIdx.x;
    const int t = threadIdx.x, lane = t & 63, wv = t >> 6;
    const int l15 = lane & 15, lh = lane >> 4;
    const int r = t >> 3, c8 = t & 7;

    // stage x[batch r][cell][c8*32 .. +32] -> fp16 LDS
    {
        const float4* src = reinterpret_cast<const float4*>(
            x + (size_t)r * (H_ * W_ * D_) + (size_t)cell * D_ + c8 * 32);
        float4 f[8];
        #pragma unroll
        for (int q = 0; q < 8; ++q) f[q] = src[q];
        #pragma unroll
        for (int s = 0; s < 4; ++s) {
            float4 a = f[2 * s], b = f[2 * s + 1];
            ushort8 o;
            o[0] = f2h(a.x); o[1] = f2h(a.y); o[2] = f2h(a.z); o[3] = f2h(a.w);
            o[4] = f2h(b.x); o[5] = f2h(b.y); o[6] = f2h(b.z); o[7] = f2h(b.w);
            int ob = c8 * 64 + s * 16;
            *reinterpret_cast<ushort8*>(xs + r * 512 + swzo(r, ob)) = o;
        }
    }
    __syncthreads();

    // wave wv computes cols [wv*128, wv*128+128): 8 n-tiles, K=256
    f32x4 zero = {0.f, 0.f, 0.f, 0.f};
    f32x4 acc[2][8];
    #pragma unroll
    for (int m = 0; m < 2; ++m)
        #pragma unroll
        for (int n = 0; n < 8; ++n) acc[m][n] = zero;

    const char* ar0 = xs + l15 * 512;
    const char* ar1 = xs + (16 + l15) * 512;
    #pragma unroll
    for (int ks = 0; ks < 8; ++ks) {
        int ob = ks * 64 + lh * 16;
        int oo = swzo(l15, ob);  // (16+l15)&7 == l15&7: same fold for both rows
        half8 af0 = *reinterpret_cast<const half8*>(ar0 + oo);
        half8 af1 = *reinterpret_cast<const half8*>(ar1 + oo);
        #pragma unroll
        for (int ntg = 0; ntg < 8; ++ntg) {
            int col = wv * 128 + ntg * 16 + l15;
            half8 bf = *reinterpret_cast<const half8*>(waxT + (size_t)col * D_ + ks * 32 + lh * 8);
            acc[0][ntg] = __builtin_amdgcn_mfma_f32_16x16x32_f16(af0, bf, acc[0][ntg], 0, 0, 0);
            acc[1][ntg] = __builtin_amdgcn_mfma_f32_16x16x32_f16(af1, bf, acc[1][ntg], 0, 0, 0);
        }
    }

    // write fragment-ordered Z (+ba), 16 contiguous fp32 per lane per slot
    #pragma unroll
    for (int s = 0; s < 4; ++s) {
        float* dst = zfb + (((size_t)cell * 16 + wv * 4 + s) * 64 + lane) * 16;
        #pragma unroll
        for (int mt = 0; mt < 2; ++mt)
            #pragma unroll
            for (int ntp = 0; ntp < 2; ++ntp) {
                float bav = ba[wv * 128 + s * 32 + ntp * 16 + l15];
                f32x4 o;
                o[0] = acc[mt][s * 2 + ntp][0] + bav;
                o[1] = acc[mt][s * 2 + ntp][1] + bav;
                o[2] = acc[mt][s * 2 + ntp][2] + bav;
                o[3] = acc[mt][s * 2 + ntp][3] + bav;
                *reinterpret_cast<f32x4*>(dst + mt * 8 + ntp * 4) = o;
            }
    }
}

// Persistent recurrence: block = (column j, n-chunk nc). 256 blocks, 1/CU.
__global__ __launch_bounds__(256, 1) void mdrnn_persistent(
    const unsigned short* __restrict__ wcT2,
    const float* __restrict__ zfb,
    unsigned short* __restrict__ hgrid,
    int* flags,
    float* __restrict__ out)
{
    __shared__ char smb[32 * 2048];  // 64KB: 32 rows x (up 1024B | left 1024B), swizzled

    const int j  = (int)blockIdx.x >> 2;
    const int nc = (int)blockIdx.x & 3;
    const int t = threadIdx.x, lane = t & 63, wv = t >> 6;
    const int l15 = lane & 15, lh = lane >> 4;
    const int r = t >> 3, c8 = t & 7;
    const int gw = nc * 4 + wv;

    // recurrent weights (128 N-cols x 1024 K) in registers: 256 VGPR
    half8 breg[2][32];
    {
        const unsigned short* wb = wcT2 + (size_t)(nc * 128 + wv * 32 + l15) * KREC + lh * 8;
        #pragma unroll
        for (int nt = 0; nt < 2; ++nt)
            #pragma unroll
            for (int ks = 0; ks < 32; ++ks)
                breg[nt][ks] = *reinterpret_cast<const half8*>(wb + (size_t)nt * 16 * KREC + ks * 32);
    }

    #pragma clang loop unroll(disable)
    for (int i = 0; i < H_; ++i) {
        const int cell = i * W_ + j;

        // Z prefetch: issued before the poll, lands during the wait
        const f32x4* zp = reinterpret_cast<const f32x4*>(
            zfb + (((size_t)cell * 16 + gw) * 64 + lane) * 16);
        f32x4 z0 = zp[0], z1 = zp[1], z2 = zp[2], z3 = zp[3];

        // RELAXED sc1 polls (no per-iteration L2 invalidate); wave 0 only.
        if (wv == 0 && (i > 0 || j > 0)) {
            int* fu = flags + (cell - W_);
            int* fl = flags + (cell - 1);
            const bool nu = (i > 0), nl = (j > 0);
            int spins = 0;
            for (;;) {
                int a = nu ? __hip_atomic_load(fu, __ATOMIC_RELAXED, __HIP_MEMORY_SCOPE_AGENT) : 4;
                int b = nl ? __hip_atomic_load(fl, __ATOMIC_RELAXED, __HIP_MEMORY_SCOPE_AGENT) : 4;
                if (a >= 4 && b >= 4) break;
                if ((++spins & 255) == 0)  // staleness insurance, ~never in steady state
                    __builtin_amdgcn_fence(__ATOMIC_ACQUIRE, "agent");
                __builtin_amdgcn_s_sleep(1);
            }
        }
        __syncthreads();
        // ONE acquire per cell (all waves): vmcnt drain + buffer_inv, then frontier reads are fresh
        if (i > 0 || j > 0)
            __builtin_amdgcn_fence(__ATOMIC_ACQUIRE, "agent");

        // single-shot staging: both frontiers -> LDS (64KB, one memory phase)
        if (i > 0) {
            const ushort8* us = reinterpret_cast<const ushort8*>(
                hgrid + (size_t)(cell - W_) * CELL_ELT + (size_t)r * U_ + c8 * 64);
            ushort8 ub[8];
            #pragma unroll
            for (int s = 0; s < 8; ++s) ub[s] = us[s];
            #pragma unroll
            for (int s = 0; s < 8; ++s) {
                int ob = c8 * 128 + s * 16;
                *reinterpret_cast<ushort8*>(smb + r * 2048 + swzo(r, ob)) = ub[s];
            }
        }
        if (j > 0) {
            const ushort8* ls = reinterpret_cast<const ushort8*>(
                hgrid + (size_t)(cell - 1) * CELL_ELT + (size_t)r * U_ + c8 * 64);
            ushort8 lb[8];
            #pragma unroll
            for (int s = 0; s < 8; ++s) lb[s] = ls[s];
            #pragma unroll
            for (int s = 0; s < 8; ++s) {
                int ob = 1024 + c8 * 128 + s * 16;
                *reinterpret_cast<ushort8*>(smb + r * 2048 + swzo(r, ob)) = lb[s];
            }
        }
        __syncthreads();

        f32x4 zero = {0.f, 0.f, 0.f, 0.f};
        f32x4 acc00 = zero, acc01 = zero, acc10 = zero, acc11 = zero;
        const char* ar0 = smb + l15 * 2048;
        const char* ar1 = smb + (16 + l15) * 2048;

#define MSTEP(ks)                                                                                \
        {                                                                                        \
            int ob = (ks) * 64 + lh * 16;                                                        \
            int oo = swzo(l15, ob);                                                              \
            half8 af0 = *reinterpret_cast<const half8*>(ar0 + oo);                               \
            half8 af1 = *reinterpret_cast<const half8*>(ar1 + oo);                               \
            acc00 = __builtin_amdgcn_mfma_f32_16x16x32_f16(af0, breg[0][(ks)], acc00, 0, 0, 0);  \
            acc01 = __builtin_amdgcn_mfma_f32_16x16x32_f16(af0, breg[1][(ks)], acc01, 0, 0, 0);  \
            acc10 = __builtin_amdgcn_mfma_f32_16x16x32_f16(af1, breg[0][(ks)], acc10, 0, 0, 0);  \
            acc11 = __builtin_amdgcn_mfma_f32_16x16x32_f16(af1, breg[1][(ks)], acc11, 0, 0, 0);  \
        }
        if (i > 0) {
            #pragma unroll
            for (int ks = 0; ks < 16; ++ks) MSTEP(ks)
        }
        if (j > 0) {
            #pragma unroll
            for (int ks = 16; ks < 32; ++ks) MSTEP(ks)
        }
#undef MSTEP

        // epilogue: acc + Z, tanh, write frontier (fp16) + out (fp32)
        unsigned short* hw = hgrid + (size_t)cell * CELL_ELT;
        const bool lastcell = (i == H_ - 1) && (j == W_ - 1);
        const int col0 = nc * 128 + wv * 32 + l15;
        #pragma unroll
        for (int mt = 0; mt < 2; ++mt) {
            f32x4 a0 = mt ? acc10 : acc00;
            f32x4 a1 = mt ? acc11 : acc01;
            f32x4 zq0 = mt ? z2 : z0;
            f32x4 zq1 = mt ? z3 : z1;
            #pragma unroll
            for (int rr = 0; rr < 4; ++rr) {
                int row = mt * 16 + lh * 4 + rr;  // C/D: row=(lane>>4)*4+reg
                float v0 = fminf(fmaxf(a0[rr] + zq0[rr], -15.f), 15.f);
                float v1 = fminf(fmaxf(a1[rr] + zq1[rr], -15.f), 15.f);
                float e0 = __expf(2.f * v0), e1 = __expf(2.f * v1);
                float th0 = (e0 - 1.f) / (e0 + 1.f);
                float th1 = (e1 - 1.f) / (e1 + 1.f);
                hw[(size_t)row * U_ + col0]      = f2h(th0);
                hw[(size_t)row * U_ + col0 + 16] = f2h(th1);
                if (lastcell) {
                    out[(size_t)row * U_ + col0]      = th0;
                    out[(size_t)row * U_ + col0 + 16] = th1;
                }
            }
        }

        __syncthreads();  // each wave drains vmcnt before barrier -> all stores done
        if (t == 0)       // RELEASE: wbl2 pushes hgrid to LLC, then flag bump at LLC
            __hip_atomic_fetch_add(&flags[cell], 1, __ATOMIC_RELEASE, __HIP_MEMORY_SCOPE_AGENT);
    }
}

extern "C" void kernel_launch(void* const* d_in, const int* in_sizes, int n_in,
                              void* d_out, int out_size, void* d_ws, size_t ws_size,
                              hipStream_t stream) {
    const float* x   = (const float*)d_in[0];
    const float* wax = (const float*)d_in[1];
    const float* w0  = (const float*)d_in[2];
    const float* w1  = (const float*)d_in[3];
    const float* ba  = (const float*)d_in[4];
    float* out = (float*)d_out;

    // ws layout (total ~386 MiB; observed ws >= 512 MiB):
    // wcT2 1MiB | waxT 256KiB | flags 16KiB | (pad to 2MiB) zfb 256MiB | hgrid 128MiB
    char* w = (char*)d_ws;
    unsigned short* wcT2  = (unsigned short*)(w);
    unsigned short* waxT  = (unsigned short*)(w + (1u << 20));
    int*            flags = (int*)(w + (1u << 20) + (256u << 10));
    float*          zfb   = (float*)(w + (2u << 20));
    unsigned short* hgrid = (unsigned short*)(w + (2u << 20) + ((size_t)256 << 20));

    (void)hipMemsetAsync(flags, 0, (size_t)H_ * W_ * sizeof(int), stream);
    prep_w   <<<dim3(U_), dim3(256), 0, stream>>>(w0, w1, wcT2);
    prep_waxT<<<dim3(U_), dim3(256), 0, stream>>>(wax, waxT);
    prep_z   <<<dim3(H_ * W_), dim3(256), 0, stream>>>(x, waxT, ba, zfb);
    mdrnn_persistent<<<dim3(W_ * 4), dim3(256), 0, stream>>>(wcT2, zfb, hgrid, flags, out);
}

// Round 7
// 1111.011 us; speedup vs baseline: 3.3981x; 1.7534x over previous
//
#include <hip/hip_runtime.h>
#include <stdint.h>

#define H_ 64
#define W_ 64
#define D_ 256
#define U_ 512
#define KREC 1024           // 512 (h_up, w0) + 512 (h_left, w1)
#define CELL_ELT (32 * U_)  // elements per cell in hgrid

typedef __attribute__((ext_vector_type(8))) _Float16 half8;
typedef __attribute__((ext_vector_type(8))) unsigned short ushort8;
typedef __attribute__((ext_vector_type(4))) float f32x4;

__device__ __forceinline__ unsigned short f2h(float f) {
    _Float16 h = (_Float16)f;  // RNE
    return __builtin_bit_cast(unsigned short, h);
}

// Bank-conflict-free LDS offset: fold byte-addr bits [9:7] and row into bits [6:4].
__device__ __forceinline__ int swzo(int r, int o) {
    return o ^ (((r ^ (o >> 7)) & 7) << 4);
}

// LLC-coherent primitives (per-XCD L2 is not cross-coherent; sc0 sc1 goes to the
// device coherence point). No wbl2 / buffer_inv anywhere in the hot loop.
__device__ __forceinline__ void llc_store_h(unsigned short* p, unsigned short v) {
    asm volatile("global_store_short %0, %1, off sc0 sc1" :: "v"(p), "v"(v) : "memory");
}
__device__ __forceinline__ void llc_load2(const int* p0, const int* p1, int& a, int& b) {
    asm volatile("global_load_dword %0, %2, off sc0 sc1\n\t"
                 "global_load_dword %1, %3, off sc0 sc1\n\t"
                 "s_waitcnt vmcnt(0)"
                 : "=v"(a), "=v"(b) : "v"(p0), "v"(p1) : "memory");
}

// wcT2[n][k] fp16: [w0; w1] transposed. n in [0,512), k in [0,1024).
__global__ void prep_w(const float* __restrict__ w0,
                       const float* __restrict__ w1,
                       unsigned short* __restrict__ wcT2) {
    int n = blockIdx.x;
    for (int k = threadIdx.x; k < KREC; k += blockDim.x) {
        float v = (k < U_) ? w0[(size_t)k * U_ + n] : w1[(size_t)(k - U_) * U_ + n];
        wcT2[(size_t)n * KREC + k] = f2h(v);
    }
}

// waxT[n][k] fp16, n in [0,512), k in [0,256)
__global__ void prep_waxT(const float* __restrict__ wax,
                          unsigned short* __restrict__ waxT) {
    int n = blockIdx.x;
    for (int k = threadIdx.x; k < D_; k += blockDim.x)
        waxT[(size_t)n * D_ + k] = f2h(wax[(size_t)k * U_ + n]);
}

// Z = x@wax + ba per cell, stored FRAGMENT-ORDERED fp32:
// zfb[cell][gw 16][lane 64][16]; value idx = mt*8 + ntp*4 + rr maps to
// (row = mt*16 + (lane>>4)*4 + rr, col = gw*32 + ntp*16 + (lane&15)).
__global__ __launch_bounds__(256) void prep_z(
    const float* __restrict__ x,
    const unsigned short* __restrict__ waxT,
    const float* __restrict__ ba,
    float* __restrict__ zfb)
{
    __shared__ char xs[32 * 512];  // 16KB fp16, swizzled
    const int cell = blockIdx.x;
    const int t = threadIdx.x, lane = t & 63, wv = t >> 6;
    const int l15 = lane & 15, lh = lane >> 4;
    const int r = t >> 3, c8 = t & 7;

    {
        const float4* src = reinterpret_cast<const float4*>(
            x + (size_t)r * (H_ * W_ * D_) + (size_t)cell * D_ + c8 * 32);
        float4 f[8];
        #pragma unroll
        for (int q = 0; q < 8; ++q) f[q] = src[q];
        #pragma unroll
        for (int s = 0; s < 4; ++s) {
            float4 a = f[2 * s], b = f[2 * s + 1];
            ushort8 o;
            o[0] = f2h(a.x); o[1] = f2h(a.y); o[2] = f2h(a.z); o[3] = f2h(a.w);
            o[4] = f2h(b.x); o[5] = f2h(b.y); o[6] = f2h(b.z); o[7] = f2h(b.w);
            int ob = c8 * 64 + s * 16;
            *reinterpret_cast<ushort8*>(xs + r * 512 + swzo(r, ob)) = o;
        }
    }
    __syncthreads();

    f32x4 zero = {0.f, 0.f, 0.f, 0.f};
    f32x4 acc[2][8];
    #pragma unroll
    for (int m = 0; m < 2; ++m)
        #pragma unroll
        for (int n = 0; n < 8; ++n) acc[m][n] = zero;

    const char* ar0 = xs + l15 * 512;
    const char* ar1 = xs + (16 + l15) * 512;
    #pragma unroll
    for (int ks = 0; ks < 8; ++ks) {
        int ob = ks * 64 + lh * 16;
        int oo = swzo(l15, ob);
        half8 af0 = *reinterpret_cast<const half8*>(ar0 + oo);
        half8 af1 = *reinterpret_cast<const half8*>(ar1 + oo);
        #pragma unroll
        for (int ntg = 0; ntg < 8; ++ntg) {
            int col = wv * 128 + ntg * 16 + l15;
            half8 bf = *reinterpret_cast<const half8*>(waxT + (size_t)col * D_ + ks * 32 + lh * 8);
            acc[0][ntg] = __builtin_amdgcn_mfma_f32_16x16x32_f16(af0, bf, acc[0][ntg], 0, 0, 0);
            acc[1][ntg] = __builtin_amdgcn_mfma_f32_16x16x32_f16(af1, bf, acc[1][ntg], 0, 0, 0);
        }
    }

    #pragma unroll
    for (int s = 0; s < 4; ++s) {
        float* dst = zfb + (((size_t)cell * 16 + wv * 4 + s) * 64 + lane) * 16;
        #pragma unroll
        for (int mt = 0; mt < 2; ++mt)
            #pragma unroll
            for (int ntp = 0; ntp < 2; ++ntp) {
                float bav = ba[wv * 128 + s * 32 + ntp * 16 + l15];
                f32x4 o;
                o[0] = acc[mt][s * 2 + ntp][0] + bav;
                o[1] = acc[mt][s * 2 + ntp][1] + bav;
                o[2] = acc[mt][s * 2 + ntp][2] + bav;
                o[3] = acc[mt][s * 2 + ntp][3] + bav;
                *reinterpret_cast<f32x4*>(dst + mt * 8 + ntp * 4) = o;
            }
    }
}

// Persistent recurrence: block = (column j, n-chunk nc). 256 blocks, 1/CU.
__global__ __launch_bounds__(256, 1) void mdrnn_persistent(
    const unsigned short* __restrict__ wcT2,
    const float* __restrict__ zfb,
    unsigned short* __restrict__ hgrid,
    int* flags,
    float* __restrict__ out)
{
    __shared__ char smb[32 * 2048];  // 64KB: 32 rows x (up 1024B | left 1024B), swizzled

    const int j  = (int)blockIdx.x >> 2;
    const int nc = (int)blockIdx.x & 3;
    const int t = threadIdx.x, lane = t & 63, wv = t >> 6;
    const int l15 = lane & 15, lh = lane >> 4;
    const int r = t >> 3, c8 = t & 7;
    const int gw = nc * 4 + wv;

    // recurrent weights (128 N-cols x 1024 K) in registers: 256 VGPR
    half8 breg[2][32];
    {
        const unsigned short* wb = wcT2 + (size_t)(nc * 128 + wv * 32 + l15) * KREC + lh * 8;
        #pragma unroll
        for (int nt = 0; nt < 2; ++nt)
            #pragma unroll
            for (int ks = 0; ks < 32; ++ks)
                breg[nt][ks] = *reinterpret_cast<const half8*>(wb + (size_t)nt * 16 * KREC + ks * 32);
    }

    #pragma clang loop unroll(disable)
    for (int i = 0; i < H_; ++i) {
        const int cell = i * W_ + j;

        // Z prefetch: issued before the poll, lands during the wait
        const f32x4* zp = reinterpret_cast<const f32x4*>(
            zfb + (((size_t)cell * 16 + gw) * 64 + lane) * 16);
        f32x4 z0 = zp[0], z1 = zp[1], z2 = zp[2], z3 = zp[3];

        // wave 0 polls both flags straight from LLC each iteration (no fences)
        if (wv == 0 && (i > 0 || j > 0)) {
            const int* fu = (i > 0) ? flags + (cell - W_) : flags + (cell - 1);
            const int* fl = (j > 0) ? flags + (cell - 1) : flags + (cell - W_);
            for (;;) {
                int a, b;
                llc_load2(fu, fl, a, b);
                if (a >= 4 && b >= 4) break;
                __builtin_amdgcn_s_sleep(1);
            }
        }
        __syncthreads();

        // single-shot staging: both frontiers -> LDS (plain cacheable loads:
        // lines were written-through to LLC and never before touched by this L2)
        if (i > 0) {
            const ushort8* us = reinterpret_cast<const ushort8*>(
                hgrid + (size_t)(cell - W_) * CELL_ELT + (size_t)r * U_ + c8 * 64);
            ushort8 ub[8];
            #pragma unroll
            for (int s = 0; s < 8; ++s) ub[s] = us[s];
            #pragma unroll
            for (int s = 0; s < 8; ++s) {
                int ob = c8 * 128 + s * 16;
                *reinterpret_cast<ushort8*>(smb + r * 2048 + swzo(r, ob)) = ub[s];
            }
        }
        if (j > 0) {
            const ushort8* ls = reinterpret_cast<const ushort8*>(
                hgrid + (size_t)(cell - 1) * CELL_ELT + (size_t)r * U_ + c8 * 64);
            ushort8 lb[8];
            #pragma unroll
            for (int s = 0; s < 8; ++s) lb[s] = ls[s];
            #pragma unroll
            for (int s = 0; s < 8; ++s) {
                int ob = 1024 + c8 * 128 + s * 16;
                *reinterpret_cast<ushort8*>(smb + r * 2048 + swzo(r, ob)) = lb[s];
            }
        }
        __syncthreads();

        f32x4 zero = {0.f, 0.f, 0.f, 0.f};
        f32x4 acc00 = zero, acc01 = zero, acc10 = zero, acc11 = zero;
        const char* ar0 = smb + l15 * 2048;
        const char* ar1 = smb + (16 + l15) * 2048;

#define MSTEP(ks)                                                                                \
        {                                                                                        \
            int ob = (ks) * 64 + lh * 16;                                                        \
            int oo = swzo(l15, ob);                                                              \
            half8 af0 = *reinterpret_cast<const half8*>(ar0 + oo);                               \
            half8 af1 = *reinterpret_cast<const half8*>(ar1 + oo);                               \
            acc00 = __builtin_amdgcn_mfma_f32_16x16x32_f16(af0, breg[0][(ks)], acc00, 0, 0, 0);  \
            acc01 = __builtin_amdgcn_mfma_f32_16x16x32_f16(af0, breg[1][(ks)], acc01, 0, 0, 0);  \
            acc10 = __builtin_amdgcn_mfma_f32_16x16x32_f16(af1, breg[0][(ks)], acc10, 0, 0, 0);  \
            acc11 = __builtin_amdgcn_mfma_f32_16x16x32_f16(af1, breg[1][(ks)], acc11, 0, 0, 0);  \
        }
        if (i > 0) {
            #pragma unroll
            for (int ks = 0; ks < 16; ++ks) MSTEP(ks)
        }
        if (j > 0) {
            #pragma unroll
            for (int ks = 16; ks < 32; ++ks) MSTEP(ks)
        }
#undef MSTEP

        // epilogue: acc + Z, tanh; frontier via write-through-to-LLC stores
        unsigned short* hw = hgrid + (size_t)cell * CELL_ELT;
        const bool lastcell = (i == H_ - 1) && (j == W_ - 1);
        const int col0 = nc * 128 + wv * 32 + l15;
        #pragma unroll
        for (int mt = 0; mt < 2; ++mt) {
            f32x4 a0 = mt ? acc10 : acc00;
            f32x4 a1 = mt ? acc11 : acc01;
            f32x4 zq0 = mt ? z2 : z0;
            f32x4 zq1 = mt ? z3 : z1;
            #pragma unroll
            for (int rr = 0; rr < 4; ++rr) {
                int row = mt * 16 + lh * 4 + rr;  // C/D: row=(lane>>4)*4+reg
                float v0 = fminf(fmaxf(a0[rr] + zq0[rr], -15.f), 15.f);
                float v1 = fminf(fmaxf(a1[rr] + zq1[rr], -15.f), 15.f);
                float e0 = __expf(2.f * v0), e1 = __expf(2.f * v1);
                float th0 = (e0 - 1.f) / (e0 + 1.f);
                float th1 = (e1 - 1.f) / (e1 + 1.f);
                llc_store_h(hw + (size_t)row * U_ + col0,      f2h(th0));
                llc_store_h(hw + (size_t)row * U_ + col0 + 16, f2h(th1));
                if (lastcell) {
                    out[(size_t)row * U_ + col0]      = th0;
                    out[(size_t)row * U_ + col0 + 16] = th1;
                }
            }
        }

        // all write-through stores acked at LLC before the barrier...
        asm volatile("s_waitcnt vmcnt(0)" ::: "memory");
        __syncthreads();
        // ...then a RELAXED flag bump (atomic executes at LLC; no wbl2)
        if (t == 0)
            __hip_atomic_fetch_add(&flags[cell], 1, __ATOMIC_RELAXED, __HIP_MEMORY_SCOPE_AGENT);
    }
}

extern "C" void kernel_launch(void* const* d_in, const int* in_sizes, int n_in,
                              void* d_out, int out_size, void* d_ws, size_t ws_size,
                              hipStream_t stream) {
    const float* x   = (const float*)d_in[0];
    const float* wax = (const float*)d_in[1];
    const float* w0  = (const float*)d_in[2];
    const float* w1  = (const float*)d_in[3];
    const float* ba  = (const float*)d_in[4];
    float* out = (float*)d_out;

    // ws layout (total ~386 MiB; observed ws >= 512 MiB):
    // wcT2 1MiB | waxT 256KiB | flags 16KiB | (pad to 2MiB) zfb 256MiB | hgrid 128MiB
    char* w = (char*)d_ws;
    unsigned short* wcT2  = (unsigned short*)(w);
    unsigned short* waxT  = (unsigned short*)(w + (1u << 20));
    int*            flags = (int*)(w + (1u << 20) + (256u << 10));
    float*          zfb   = (float*)(w + (2u << 20));
    unsigned short* hgrid = (unsigned short*)(w + (2u << 20) + ((size_t)256 << 20));

    (void)hipMemsetAsync(flags, 0, (size_t)H_ * W_ * sizeof(int), stream);
    prep_w   <<<dim3(U_), dim3(256), 0, stream>>>(w0, w1, wcT2);
    prep_waxT<<<dim3(U_), dim3(256), 0, stream>>>(wax, waxT);
    prep_z   <<<dim3(H_ * W_), dim3(256), 0, stream>>>(x, waxT, ba, zfb);
    mdrnn_persistent<<<dim3(W_ * 4), dim3(256), 0, stream>>>(wcT2, zfb, hgrid, flags, out);
}

// Round 9
// 1081.426 us; speedup vs baseline: 3.4911x; 1.0274x over previous
//
#include <hip/hip_runtime.h>
#include <stdint.h>

#define H_ 64
#define W_ 64
#define D_ 256
#define U_ 512
#define KREC 1024           // 512 (h_up, w0) + 512 (h_left, w1)
#define CELL_ELT (32 * U_)  // elements per cell in hgrid

typedef __attribute__((ext_vector_type(8))) _Float16 half8;
typedef __attribute__((ext_vector_type(8))) unsigned short ushort8;
typedef __attribute__((ext_vector_type(4))) float f32x4;

__device__ __forceinline__ unsigned short f2h(float f) {
    _Float16 h = (_Float16)f;  // RNE
    return __builtin_bit_cast(unsigned short, h);
}

// Bank-conflict-free LDS offset: fold byte-addr bits [9:7] and row into bits [6:4].
__device__ __forceinline__ int swzo(int r, int o) {
    return o ^ (((r ^ (o >> 7)) & 7) << 4);
}

// LLC-coherent poll (per-XCD L2 not cross-coherent; sc0 sc1 = coherence point).
__device__ __forceinline__ void llc_load2(const int* p0, const int* p1, int& a, int& b) {
    asm volatile("global_load_dword %0, %2, off sc0 sc1\n\t"
                 "global_load_dword %1, %3, off sc0 sc1\n\t"
                 "s_waitcnt vmcnt(0)"
                 : "=v"(a), "=v"(b) : "v"(p0), "v"(p1) : "memory");
}

// wcT2[n][k] fp16: [w0; w1] transposed. n in [0,512), k in [0,1024).
__global__ void prep_w(const float* __restrict__ w0,
                       const float* __restrict__ w1,
                       unsigned short* __restrict__ wcT2) {
    int n = blockIdx.x;
    for (int k = threadIdx.x; k < KREC; k += blockDim.x) {
        float v = (k < U_) ? w0[(size_t)k * U_ + n] : w1[(size_t)(k - U_) * U_ + n];
        wcT2[(size_t)n * KREC + k] = f2h(v);
    }
}

// waxT[n][k] fp16, n in [0,512), k in [0,256)
__global__ void prep_waxT(const float* __restrict__ wax,
                          unsigned short* __restrict__ waxT) {
    int n = blockIdx.x;
    for (int k = threadIdx.x; k < D_; k += blockDim.x)
        waxT[(size_t)n * D_ + k] = f2h(wax[(size_t)k * U_ + n]);
}

// Z = x@wax + ba per cell, stored FRAGMENT-ORDERED fp32:
// zfb[cell][gw 16][lane 64][16]; value idx = mt*8 + ntp*4 + rr maps to
// (row = mt*16 + (lane>>4)*4 + rr, col = gw*32 + ntp*16 + (lane&15)).
__global__ __launch_bounds__(256) void prep_z(
    const float* __restrict__ x,
    const unsigned short* __restrict__ waxT,
    const float* __restrict__ ba,
    float* __restrict__ zfb)
{
    __shared__ char xs[32 * 512];  // 16KB fp16, swizzled
    const int cell = blockIdx.x;
    const int t = threadIdx.x, lane = t & 63, wv = t >> 6;
    const int l15 = lane & 15, lh = lane >> 4;
    const int r = t >> 3, c8 = t & 7;

    {
        const float4* src = reinterpret_cast<const float4*>(
            x + (size_t)r * (H_ * W_ * D_) + (size_t)cell * D_ + c8 * 32);
        float4 f[8];
        #pragma unroll
        for (int q = 0; q < 8; ++q) f[q] = src[q];
        #pragma unroll
        for (int s = 0; s < 4; ++s) {
            float4 a = f[2 * s], b = f[2 * s + 1];
            ushort8 o;
            o[0] = f2h(a.x); o[1] = f2h(a.y); o[2] = f2h(a.z); o[3] = f2h(a.w);
            o[4] = f2h(b.x); o[5] = f2h(b.y); o[6] = f2h(b.z); o[7] = f2h(b.w);
            int ob = c8 * 64 + s * 16;
            *reinterpret_cast<ushort8*>(xs + r * 512 + swzo(r, ob)) = o;
        }
    }
    __syncthreads();

    f32x4 zero = {0.f, 0.f, 0.f, 0.f};
    f32x4 acc[2][8];
    #pragma unroll
    for (int m = 0; m < 2; ++m)
        #pragma unroll
        for (int n = 0; n < 8; ++n) acc[m][n] = zero;

    const char* ar0 = xs + l15 * 512;
    const char* ar1 = xs + (16 + l15) * 512;
    #pragma unroll
    for (int ks = 0; ks < 8; ++ks) {
        int ob = ks * 64 + lh * 16;
        int oo = swzo(l15, ob);
        half8 af0 = *reinterpret_cast<const half8*>(ar0 + oo);
        half8 af1 = *reinterpret_cast<const half8*>(ar1 + oo);
        #pragma unroll
        for (int ntg = 0; ntg < 8; ++ntg) {
            int col = wv * 128 + ntg * 16 + l15;
            half8 bf = *reinterpret_cast<const half8*>(waxT + (size_t)col * D_ + ks * 32 + lh * 8);
            acc[0][ntg] = __builtin_amdgcn_mfma_f32_16x16x32_f16(af0, bf, acc[0][ntg], 0, 0, 0);
            acc[1][ntg] = __builtin_amdgcn_mfma_f32_16x16x32_f16(af1, bf, acc[1][ntg], 0, 0, 0);
        }
    }

    #pragma unroll
    for (int s = 0; s < 4; ++s) {
        float* dst = zfb + (((size_t)cell * 16 + wv * 4 + s) * 64 + lane) * 16;
        #pragma unroll
        for (int mt = 0; mt < 2; ++mt)
            #pragma unroll
            for (int ntp = 0; ntp < 2; ++ntp) {
                float bav = ba[wv * 128 + s * 32 + ntp * 16 + l15];
                f32x4 o;
                o[0] = acc[mt][s * 2 + ntp][0] + bav;
                o[1] = acc[mt][s * 2 + ntp][1] + bav;
                o[2] = acc[mt][s * 2 + ntp][2] + bav;
                o[3] = acc[mt][s * 2 + ntp][3] + bav;
                *reinterpret_cast<f32x4*>(dst + mt * 8 + ntp * 4) = o;
            }
    }
}

// Persistent recurrence: block = (column j, n-chunk nc). 256 blocks, 1/CU.
__global__ __launch_bounds__(256, 1) void mdrnn_persistent(
    const unsigned short* __restrict__ wcT2,
    const float* __restrict__ zfb,
    unsigned short* __restrict__ hgrid,
    int* flags,
    float* __restrict__ out)
{
    __shared__ char smb[32 * 2048];          // 64KB staging: 32 rows x (up | left)
    __shared__ unsigned long long heps64[32 * 32];  // 8KB epilogue transpose, LINEAR
    unsigned short* heps16 = reinterpret_cast<unsigned short*>(heps64);

    const int j  = (int)blockIdx.x >> 2;
    const int nc = (int)blockIdx.x & 3;
    const int t = threadIdx.x, lane = t & 63, wv = t >> 6;
    const int l15 = lane & 15, lh = lane >> 4;
    const int r = t >> 3, c8 = t & 7;
    const int gw = nc * 4 + wv;

    // recurrent weights (128 N-cols x 1024 K) in registers: 256 VGPR
    half8 breg[2][32];
    {
        const unsigned short* wb = wcT2 + (size_t)(nc * 128 + wv * 32 + l15) * KREC + lh * 8;
        #pragma unroll
        for (int nt = 0; nt < 2; ++nt)
            #pragma unroll
            for (int ks = 0; ks < 32; ++ks)
                breg[nt][ks] = *reinterpret_cast<const half8*>(wb + (size_t)nt * 16 * KREC + ks * 32);
    }

    #pragma clang loop unroll(disable)
    for (int i = 0; i < H_; ++i) {
        const int cell = i * W_ + j;

        // Z prefetch: issued before the poll, lands during the wait
        const f32x4* zp = reinterpret_cast<const f32x4*>(
            zfb + (((size_t)cell * 16 + gw) * 64 + lane) * 16);
        f32x4 z0 = zp[0], z1 = zp[1], z2 = zp[2], z3 = zp[3];

        // wave 0 polls both flags straight from LLC each iteration (no fences)
        if (wv == 0 && (i > 0 || j > 0)) {
            const int* fu = (i > 0) ? flags + (cell - W_) : flags + (cell - 1);
            const int* fl = (j > 0) ? flags + (cell - 1) : flags + (cell - W_);
            for (;;) {
                int a, b;
                llc_load2(fu, fl, a, b);
                if (a >= 4 && b >= 4) break;
                __builtin_amdgcn_s_sleep(1);
            }
        }
        __syncthreads();

        // single-shot staging: both frontiers -> LDS
        if (i > 0) {
            const ushort8* us = reinterpret_cast<const ushort8*>(
                hgrid + (size_t)(cell - W_) * CELL_ELT + (size_t)r * U_ + c8 * 64);
            ushort8 ub[8];
            #pragma unroll
            for (int s = 0; s < 8; ++s) ub[s] = us[s];
            #pragma unroll
            for (int s = 0; s < 8; ++s) {
                int ob = c8 * 128 + s * 16;
                *reinterpret_cast<ushort8*>(smb + r * 2048 + swzo(r, ob)) = ub[s];
            }
        }
        if (j > 0) {
            const ushort8* ls = reinterpret_cast<const ushort8*>(
                hgrid + (size_t)(cell - 1) * CELL_ELT + (size_t)r * U_ + c8 * 64);
            ushort8 lb[8];
            #pragma unroll
            for (int s = 0; s < 8; ++s) lb[s] = ls[s];
            #pragma unroll
            for (int s = 0; s < 8; ++s) {
                int ob = 1024 + c8 * 128 + s * 16;
                *reinterpret_cast<ushort8*>(smb + r * 2048 + swzo(r, ob)) = lb[s];
            }
        }
        __syncthreads();

        f32x4 zero = {0.f, 0.f, 0.f, 0.f};
        f32x4 acc00 = zero, acc01 = zero, acc10 = zero, acc11 = zero;
        const char* ar0 = smb + l15 * 2048;
        const char* ar1 = smb + (16 + l15) * 2048;

#define MSTEP(ks)                                                                                \
        {                                                                                        \
            int ob = (ks) * 64 + lh * 16;                                                        \
            int oo = swzo(l15, ob);                                                              \
            half8 af0 = *reinterpret_cast<const half8*>(ar0 + oo);                               \
            half8 af1 = *reinterpret_cast<const half8*>(ar1 + oo);                               \
            acc00 = __builtin_amdgcn_mfma_f32_16x16x32_f16(af0, breg[0][(ks)], acc00, 0, 0, 0);  \
            acc01 = __builtin_amdgcn_mfma_f32_16x16x32_f16(af0, breg[1][(ks)], acc01, 0, 0, 0);  \
            acc10 = __builtin_amdgcn_mfma_f32_16x16x32_f16(af1, breg[0][(ks)], acc10, 0, 0, 0);  \
            acc11 = __builtin_amdgcn_mfma_f32_16x16x32_f16(af1, breg[1][(ks)], acc11, 0, 0, 0);  \
        }
        if (i > 0) {
            #pragma unroll
            for (int ks = 0; ks < 16; ++ks) MSTEP(ks)
        }
        if (j > 0) {
            #pragma unroll
            for (int ks = 16; ks < 32; ++ks) MSTEP(ks)
        }
#undef MSTEP

        // epilogue phase 1: acc + Z, tanh -> heps16 (LINEAR [32 rows][128 cols])
        const bool lastcell = (i == H_ - 1) && (j == W_ - 1);
        const int col0 = nc * 128 + wv * 32 + l15;
        #pragma unroll
        for (int mt = 0; mt < 2; ++mt) {
            f32x4 a0 = mt ? acc10 : acc00;
            f32x4 a1 = mt ? acc11 : acc01;
            f32x4 zq0 = mt ? z2 : z0;
            f32x4 zq1 = mt ? z3 : z1;
            #pragma unroll
            for (int rr = 0; rr < 4; ++rr) {
                int row = mt * 16 + lh * 4 + rr;  // C/D: row=(lane>>4)*4+reg
                float v0 = fminf(fmaxf(a0[rr] + zq0[rr], -15.f), 15.f);
                float v1 = fminf(fmaxf(a1[rr] + zq1[rr], -15.f), 15.f);
                float e0 = __expf(2.f * v0), e1 = __expf(2.f * v1);
                float th0 = (e0 - 1.f) / (e0 + 1.f);
                float th1 = (e1 - 1.f) / (e1 + 1.f);
                heps16[row * 128 + wv * 32 + l15]      = f2h(th0);
                heps16[row * 128 + wv * 32 + 16 + l15] = f2h(th1);
                if (lastcell) {
                    out[(size_t)row * U_ + col0]      = th0;
                    out[(size_t)row * U_ + col0 + 16] = th1;
                }
            }
        }
        __syncthreads();  // transpose complete

        // epilogue phase 2: coalesced agent-scope stores (4 x 8B per thread,
        // lane-contiguous per instruction: 8 lanes x 8B = 64B runs)
        {
            const int erow = t >> 3, e = t & 7;
            unsigned long long* gq = reinterpret_cast<unsigned long long*>(
                hgrid + (size_t)cell * CELL_ELT + (size_t)erow * U_ + nc * 128);
            #pragma unroll
            for (int q = 0; q < 4; ++q) {
                unsigned long long v = heps64[erow * 32 + q * 8 + e];
                __hip_atomic_store(gq + q * 8 + e, v, __ATOMIC_RELAXED, __HIP_MEMORY_SCOPE_AGENT);
            }
        }

        // all agent stores acked at LLC before the barrier...
        asm volatile("s_waitcnt vmcnt(0)" ::: "memory");
        __syncthreads();
        // ...then a RELAXED flag bump (atomic executes at LLC; no wbl2)
        if (t == 0)
            __hip_atomic_fetch_add(&flags[cell], 1, __ATOMIC_RELAXED, __HIP_MEMORY_SCOPE_AGENT);
    }
}

extern "C" void kernel_launch(void* const* d_in, const int* in_sizes, int n_in,
                              void* d_out, int out_size, void* d_ws, size_t ws_size,
                              hipStream_t stream) {
    const float* x   = (const float*)d_in[0];
    const float* wax = (const float*)d_in[1];
    const float* w0  = (const float*)d_in[2];
    const float* w1  = (const float*)d_in[3];
    const float* ba  = (const float*)d_in[4];
    float* out = (float*)d_out;

    // ws layout (total ~386 MiB; observed ws >= 512 MiB):
    // wcT2 1MiB | waxT 256KiB | flags 16KiB | (pad to 2MiB) zfb 256MiB | hgrid 128MiB
    char* w = (char*)d_ws;
    unsigned short* wcT2  = (unsigned short*)(w);
    unsigned short* waxT  = (unsigned short*)(w + (1u << 20));
    int*            flags = (int*)(w + (1u << 20) + (256u << 10));
    float*          zfb   = (float*)(w + (2u << 20));
    unsigned short* hgrid = (unsigned short*)(w + (2u << 20) + ((size_t)256 << 20));

    (void)hipMemsetAsync(flags, 0, (size_t)H_ * W_ * sizeof(int), stream);
    prep_w   <<<dim3(U_), dim3(256), 0, stream>>>(w0, w1, wcT2);
    prep_waxT<<<dim3(U_), dim3(256), 0, stream>>>(wax, waxT);
    prep_z   <<<dim3(H_ * W_), dim3(256), 0, stream>>>(x, waxT, ba, zfb);
    mdrnn_persistent<<<dim3(W_ * 4), dim3(256), 0, stream>>>(wcT2, zfb, hgrid, flags, out);
}

// Round 10
// 1065.730 us; speedup vs baseline: 3.5425x; 1.0147x over previous
//
#include <hip/hip_runtime.h>
#include <stdint.h>

#define H_ 64
#define W_ 64
#define D_ 256
#define U_ 512
#define KREC 1024           // 512 (h_up, w0) + 512 (h_left, w1)
#define CELL_ELT (32 * U_)  // elements per cell in hgrid

typedef __attribute__((ext_vector_type(8))) _Float16 half8;
typedef __attribute__((ext_vector_type(8))) unsigned short ushort8;
typedef __attribute__((ext_vector_type(4))) float f32x4;

__device__ __forceinline__ unsigned short f2h(float f) {
    _Float16 h = (_Float16)f;  // RNE
    return __builtin_bit_cast(unsigned short, h);
}

// Bank-conflict-free LDS offset: fold byte-addr bits [9:7] and row into bits [6:4].
__device__ __forceinline__ int swzo(int r, int o) {
    return o ^ (((r ^ (o >> 7)) & 7) << 4);
}

// wcT2[n][k] fp16: [w0; w1] transposed. n in [0,512), k in [0,1024).
__global__ void prep_w(const float* __restrict__ w0,
                       const float* __restrict__ w1,
                       unsigned short* __restrict__ wcT2) {
    int n = blockIdx.x;
    for (int k = threadIdx.x; k < KREC; k += blockDim.x) {
        float v = (k < U_) ? w0[(size_t)k * U_ + n] : w1[(size_t)(k - U_) * U_ + n];
        wcT2[(size_t)n * KREC + k] = f2h(v);
    }
}

// waxT[n][k] fp16, n in [0,512), k in [0,256)
__global__ void prep_waxT(const float* __restrict__ wax,
                          unsigned short* __restrict__ waxT) {
    int n = blockIdx.x;
    for (int k = threadIdx.x; k < D_; k += blockDim.x)
        waxT[(size_t)n * D_ + k] = f2h(wax[(size_t)k * U_ + n]);
}

// Z = x@wax + ba per cell, stored FRAGMENT-ORDERED fp32:
// zfb[cell][gw 16][lane 64][16]; value idx = mt*8 + ntp*4 + rr maps to
// (row = mt*16 + (lane>>4)*4 + rr, col = gw*32 + ntp*16 + (lane&15)).
__global__ __launch_bounds__(256) void prep_z(
    const float* __restrict__ x,
    const unsigned short* __restrict__ waxT,
    const float* __restrict__ ba,
    float* __restrict__ zfb)
{
    __shared__ char xs[32 * 512];  // 16KB fp16, swizzled
    const int cell = blockIdx.x;
    const int t = threadIdx.x, lane = t & 63, wv = t >> 6;
    const int l15 = lane & 15, lh = lane >> 4;
    const int r = t >> 3, c8 = t & 7;

    {
        const float4* src = reinterpret_cast<const float4*>(
            x + (size_t)r * (H_ * W_ * D_) + (size_t)cell * D_ + c8 * 32);
        float4 f[8];
        #pragma unroll
        for (int q = 0; q < 8; ++q) f[q] = src[q];
        #pragma unroll
        for (int s = 0; s < 4; ++s) {
            float4 a = f[2 * s], b = f[2 * s + 1];
            ushort8 o;
            o[0] = f2h(a.x); o[1] = f2h(a.y); o[2] = f2h(a.z); o[3] = f2h(a.w);
            o[4] = f2h(b.x); o[5] = f2h(b.y); o[6] = f2h(b.z); o[7] = f2h(b.w);
            int ob = c8 * 64 + s * 16;
            *reinterpret_cast<ushort8*>(xs + r * 512 + swzo(r, ob)) = o;
        }
    }
    __syncthreads();

    f32x4 zero = {0.f, 0.f, 0.f, 0.f};
    f32x4 acc[2][8];
    #pragma unroll
    for (int m = 0; m < 2; ++m)
        #pragma unroll
        for (int n = 0; n < 8; ++n) acc[m][n] = zero;

    const char* ar0 = xs + l15 * 512;
    const char* ar1 = xs + (16 + l15) * 512;
    #pragma unroll
    for (int ks = 0; ks < 8; ++ks) {
        int ob = ks * 64 + lh * 16;
        int oo = swzo(l15, ob);
        half8 af0 = *reinterpret_cast<const half8*>(ar0 + oo);
        half8 af1 = *reinterpret_cast<const half8*>(ar1 + oo);
        #pragma unroll
        for (int ntg = 0; ntg < 8; ++ntg) {
            int col = wv * 128 + ntg * 16 + l15;
            half8 bf = *reinterpret_cast<const half8*>(waxT + (size_t)col * D_ + ks * 32 + lh * 8);
            acc[0][ntg] = __builtin_amdgcn_mfma_f32_16x16x32_f16(af0, bf, acc[0][ntg], 0, 0, 0);
            acc[1][ntg] = __builtin_amdgcn_mfma_f32_16x16x32_f16(af1, bf, acc[1][ntg], 0, 0, 0);
        }
    }

    #pragma unroll
    for (int s = 0; s < 4; ++s) {
        float* dst = zfb + (((size_t)cell * 16 + wv * 4 + s) * 64 + lane) * 16;
        #pragma unroll
        for (int mt = 0; mt < 2; ++mt)
            #pragma unroll
            for (int ntp = 0; ntp < 2; ++ntp) {
                float bav = ba[wv * 128 + s * 32 + ntp * 16 + l15];
                f32x4 o;
                o[0] = acc[mt][s * 2 + ntp][0] + bav;
                o[1] = acc[mt][s * 2 + ntp][1] + bav;
                o[2] = acc[mt][s * 2 + ntp][2] + bav;
                o[3] = acc[mt][s * 2 + ntp][3] + bav;
                *reinterpret_cast<f32x4*>(dst + mt * 8 + ntp * 4) = o;
            }
    }
}

// Persistent recurrence: block = (column j, n-chunk nc). 256 blocks, 1/CU.
// flags2[cell*16 + nc] = 1 when chunk nc of cell is published (cell stride 64B).
__global__ __launch_bounds__(256, 1) void mdrnn_persistent(
    const unsigned short* __restrict__ wcT2,
    const float* __restrict__ zfb,
    unsigned short* __restrict__ hgrid,
    int* flags2,
    float* __restrict__ out)
{
    __shared__ char smb[32 * 2048];          // 64KB staging: 32 rows x (up | left)
    __shared__ unsigned long long heps64[32 * 32];  // 8KB epilogue transpose, LINEAR
    unsigned short* heps16 = reinterpret_cast<unsigned short*>(heps64);

    const int j  = (int)blockIdx.x >> 2;
    const int nc = (int)blockIdx.x & 3;
    const int t = threadIdx.x, lane = t & 63, wv = t >> 6;
    const int l15 = lane & 15, lh = lane >> 4;
    const int r = t >> 3, c8 = t & 7;
    const int gw = nc * 4 + wv;
    const unsigned long long RDY2 = 0x0000000100000001ULL;

    // recurrent weights (128 N-cols x 1024 K) in registers: 256 VGPR
    half8 breg[2][32];
    {
        const unsigned short* wb = wcT2 + (size_t)(nc * 128 + wv * 32 + l15) * KREC + lh * 8;
        #pragma unroll
        for (int nt = 0; nt < 2; ++nt)
            #pragma unroll
            for (int ks = 0; ks < 32; ++ks)
                breg[nt][ks] = *reinterpret_cast<const half8*>(wb + (size_t)nt * 16 * KREC + ks * 32);
    }

    #pragma clang loop unroll(disable)
    for (int i = 0; i < H_; ++i) {
        const int cell = i * W_ + j;

        // Z prefetch: issued before the poll, lands during the wait
        const f32x4* zp = reinterpret_cast<const f32x4*>(
            zfb + (((size_t)cell * 16 + gw) * 64 + lane) * 16);
        f32x4 z0 = zp[0], z1 = zp[1], z2 = zp[2], z3 = zp[3];

        // ALL waves poll (uniform addresses -> coalesced); each wave proceeds
        // straight to its staging share on detection (no post-detect barrier;
        // the previous iteration's pre-flag barrier separates LDS hazards).
        if (i > 0 || j > 0) {
            const unsigned long long* fu = reinterpret_cast<const unsigned long long*>(
                flags2 + (size_t)(cell - W_) * 16);
            const unsigned long long* fl = reinterpret_cast<const unsigned long long*>(
                flags2 + (size_t)(cell - 1) * 16);
            const bool nu = (i > 0), nl = (j > 0);
            for (;;) {
                bool ok = true;
                if (nu) {
                    unsigned long long a = __hip_atomic_load(fu,     __ATOMIC_RELAXED, __HIP_MEMORY_SCOPE_AGENT);
                    unsigned long long b = __hip_atomic_load(fu + 1, __ATOMIC_RELAXED, __HIP_MEMORY_SCOPE_AGENT);
                    ok = ok && (a == RDY2) && (b == RDY2);
                }
                if (nl) {
                    unsigned long long a = __hip_atomic_load(fl,     __ATOMIC_RELAXED, __HIP_MEMORY_SCOPE_AGENT);
                    unsigned long long b = __hip_atomic_load(fl + 1, __ATOMIC_RELAXED, __HIP_MEMORY_SCOPE_AGENT);
                    ok = ok && (a == RDY2) && (b == RDY2);
                }
                if (ok) break;
                __builtin_amdgcn_s_sleep(1);
            }
        }
        asm volatile("" ::: "memory");  // no staging-load hoisting above the poll

        // single-shot staging: both frontiers -> LDS (plain cacheable loads;
        // lines were written through to LLC and never touched by this L2)
        if (i > 0) {
            const ushort8* us = reinterpret_cast<const ushort8*>(
                hgrid + (size_t)(cell - W_) * CELL_ELT + (size_t)r * U_ + c8 * 64);
            ushort8 ub[8];
            #pragma unroll
            for (int s = 0; s < 8; ++s) ub[s] = us[s];
            #pragma unroll
            for (int s = 0; s < 8; ++s) {
                int ob = c8 * 128 + s * 16;
                *reinterpret_cast<ushort8*>(smb + r * 2048 + swzo(r, ob)) = ub[s];
            }
        }
        if (j > 0) {
            const ushort8* ls = reinterpret_cast<const ushort8*>(
                hgrid + (size_t)(cell - 1) * CELL_ELT + (size_t)r * U_ + c8 * 64);
            ushort8 lb[8];
            #pragma unroll
            for (int s = 0; s < 8; ++s) lb[s] = ls[s];
            #pragma unroll
            for (int s = 0; s < 8; ++s) {
                int ob = 1024 + c8 * 128 + s * 16;
                *reinterpret_cast<ushort8*>(smb + r * 2048 + swzo(r, ob)) = lb[s];
            }
        }
        __syncthreads();  // B_stage: staging complete before fragment reads

        f32x4 zero = {0.f, 0.f, 0.f, 0.f};
        f32x4 acc00 = zero, acc01 = zero, acc10 = zero, acc11 = zero;
        const char* ar0 = smb + l15 * 2048;
        const char* ar1 = smb + (16 + l15) * 2048;

#define MSTEP(ks)                                                                                \
        {                                                                                        \
            int ob = (ks) * 64 + lh * 16;                                                        \
            int oo = swzo(l15, ob);                                                              \
            half8 af0 = *reinterpret_cast<const half8*>(ar0 + oo);                               \
            half8 af1 = *reinterpret_cast<const half8*>(ar1 + oo);                               \
            acc00 = __builtin_amdgcn_mfma_f32_16x16x32_f16(af0, breg[0][(ks)], acc00, 0, 0, 0);  \
            acc01 = __builtin_amdgcn_mfma_f32_16x16x32_f16(af0, breg[1][(ks)], acc01, 0, 0, 0);  \
            acc10 = __builtin_amdgcn_mfma_f32_16x16x32_f16(af1, breg[0][(ks)], acc10, 0, 0, 0);  \
            acc11 = __builtin_amdgcn_mfma_f32_16x16x32_f16(af1, breg[1][(ks)], acc11, 0, 0, 0);  \
        }
        if (i > 0) {
            #pragma unroll
            for (int ks = 0; ks < 16; ++ks) MSTEP(ks)
        }
        if (j > 0) {
            #pragma unroll
            for (int ks = 16; ks < 32; ++ks) MSTEP(ks)
        }
#undef MSTEP

        // epilogue phase 1: acc + Z, tanh -> heps16 (LINEAR [32 rows][128 cols])
        const bool lastcell = (i == H_ - 1) && (j == W_ - 1);
        const int col0 = nc * 128 + wv * 32 + l15;
        #pragma unroll
        for (int mt = 0; mt < 2; ++mt) {
            f32x4 a0 = mt ? acc10 : acc00;
            f32x4 a1 = mt ? acc11 : acc01;
            f32x4 zq0 = mt ? z2 : z0;
            f32x4 zq1 = mt ? z3 : z1;
            #pragma unroll
            for (int rr = 0; rr < 4; ++rr) {
                int row = mt * 16 + lh * 4 + rr;  // C/D: row=(lane>>4)*4+reg
                float v0 = fminf(fmaxf(a0[rr] + zq0[rr], -15.f), 15.f);
                float v1 = fminf(fmaxf(a1[rr] + zq1[rr], -15.f), 15.f);
                float e0 = __expf(2.f * v0), e1 = __expf(2.f * v1);
                float th0 = (e0 - 1.f) / (e0 + 1.f);
                float th1 = (e1 - 1.f) / (e1 + 1.f);
                heps16[row * 128 + wv * 32 + l15]      = f2h(th0);
                heps16[row * 128 + wv * 32 + 16 + l15] = f2h(th1);
                if (lastcell) {
                    out[(size_t)row * U_ + col0]      = th0;
                    out[(size_t)row * U_ + col0 + 16] = th1;
                }
            }
        }
        __syncthreads();  // B_t: transpose complete

        // epilogue phase 2: coalesced agent-scope stores (4 x 8B per thread)
        {
            const int erow = t >> 3, e = t & 7;
            unsigned long long* gq = reinterpret_cast<unsigned long long*>(
                hgrid + (size_t)cell * CELL_ELT + (size_t)erow * U_ + nc * 128);
            #pragma unroll
            for (int q = 0; q < 4; ++q) {
                unsigned long long v = heps64[erow * 32 + q * 8 + e];
                __hip_atomic_store(gq + q * 8 + e, v, __ATOMIC_RELAXED, __HIP_MEMORY_SCOPE_AGENT);
            }
        }

        // all agent stores acked at LLC before the barrier...
        asm volatile("s_waitcnt vmcnt(0)" ::: "memory");
        __syncthreads();  // B_f: also separates this iter's LDS reads from next staging
        // ...then publish this chunk: plain agent store, no RMW
        if (t == 0)
            __hip_atomic_store(&flags2[(size_t)cell * 16 + nc], 1,
                               __ATOMIC_RELAXED, __HIP_MEMORY_SCOPE_AGENT);
    }
}

extern "C" void kernel_launch(void* const* d_in, const int* in_sizes, int n_in,
                              void* d_out, int out_size, void* d_ws, size_t ws_size,
                              hipStream_t stream) {
    const float* x   = (const float*)d_in[0];
    const float* wax = (const float*)d_in[1];
    const float* w0  = (const float*)d_in[2];
    const float* w1  = (const float*)d_in[3];
    const float* ba  = (const float*)d_in[4];
    float* out = (float*)d_out;

    // ws layout (total ~386 MiB; observed ws >= 512 MiB):
    // wcT2 1MiB | waxT 256KiB | flags2 256KiB | (pad to 2MiB) zfb 256MiB | hgrid 128MiB
    char* w = (char*)d_ws;
    unsigned short* wcT2   = (unsigned short*)(w);
    unsigned short* waxT   = (unsigned short*)(w + (1u << 20));
    int*            flags2 = (int*)(w + (1u << 20) + (256u << 10));
    float*          zfb    = (float*)(w + (2u << 20));
    unsigned short* hgrid  = (unsigned short*)(w + (2u << 20) + ((size_t)256 << 20));

    (void)hipMemsetAsync(flags2, 0, (size_t)H_ * W_ * 16 * sizeof(int), stream);
    prep_w   <<<dim3(U_), dim3(256), 0, stream>>>(w0, w1, wcT2);
    prep_waxT<<<dim3(U_), dim3(256), 0, stream>>>(wax, waxT);
    prep_z   <<<dim3(H_ * W_), dim3(256), 0, stream>>>(x, waxT, ba, zfb);
    mdrnn_persistent<<<dim3(W_ * 4), dim3(256), 0, stream>>>(wcT2, zfb, hgrid, flags2, out);
}